// Round 13
// baseline (606.778 us; speedup 1.0000x reference)
//
#include <hip/hip_runtime.h>

#define BT 51200      // B*T
#define NB 512        // batch

// ---------- workspace float offsets ----------
#define P1_OFF   ((size_t)0)
#define X_OFF    ((size_t)20480000)
#define GX_OFF   ((size_t)0)

__device__ __forceinline__ float sigf(float x) {
  return __fdividef(1.f, 1.f + __expf(-x));
}
__device__ __forceinline__ float tanhf2(float x) {
  float ax = fabsf(x);
  float e = __expf(-2.f * ax);
  float r = __fdividef(1.f - e, 1.f + e);
  return x < 0.f ? -r : r;
}
// broadcast of lane `l` (uniform/literal index): v_readlane, VALU-only.
__device__ __forceinline__ float rl(float v, int l) {
  return __uint_as_float(__builtin_amdgcn_readlane(__float_as_uint(v), l));
}

// ============ K1 variant A (EXPERIMENTAL): 512thr / 32 items ==============
// (r10/r11: VGPR 124, FETCH 40MB, WRITE 80MB, VALUBusy 77%, 146us — clean,
// near VALU limit. Frozen.)
__global__ __launch_bounds__(512, 1)
void k1_conv1_exp(const float* __restrict__ obs, const float* __restrict__ w,
                  const float* __restrict__ bias, float* __restrict__ p1) {
  __shared__ float xs[32 * 411];   // 411 odd -> item*411 mod 32 permutation
  __shared__ float wsh[16 * 36];
  int tid = threadIdx.x;
  int phys = blockIdx.x;           // 1600 blocks
  int x8 = phys & 7;
  int rest = phys >> 3;            // 0..199
  int half = rest & 1;
  int pair = (rest >> 1) * 8 + x8; // 0..799
  int i0 = pair * 64 + half * 32;
  for (int idx = tid; idx < 12800; idx += 512) {
    int item = idx / 400, feat = idx - item * 400;
    xs[item * 411 + feat] = obs[(size_t)(i0 + item) * 400 + feat];
  }
  for (int idx = tid; idx < 576; idx += 512) wsh[idx] = w[idx];
  __syncthreads();
  int lane = tid & 63;
  int item = lane & 31;
  int oc = (tid >> 6) * 2 + (lane >> 5);
  const float* xrow = xs + item * 411;

#define LOADR(R, C, RR) do { \
  int r_ = 2 * p - 1 + (RR); \
  R[0] = 0.f; R[11] = 0.f; \
  if (r_ >= 0 && r_ <= 9) { \
    _Pragma("unroll") \
    for (int j = 0; j < 10; ++j) R[j + 1] = xrow[(C) * 100 + r_ * 10 + j]; \
  } else { \
    _Pragma("unroll") \
    for (int j = 0; j < 10; ++j) R[j + 1] = 0.f; \
  } \
} while (0)

#define FMAU(II, RA, RB, RC, C) do { \
  const float* wp_ = wsh + oc * 36 + (C) * 9; \
  float w0_ = wp_[0], w1_ = wp_[1], w2_ = wp_[2]; \
  float w3_ = wp_[3], w4_ = wp_[4], w5_ = wp_[5]; \
  float w6_ = wp_[6], w7_ = wp_[7], w8_ = wp_[8]; \
  _Pragma("unroll") \
  for (int q = 0; q < 5; ++q) { \
    _Pragma("unroll") \
    for (int jj = 0; jj < 2; ++jj) { \
      int cb = 2 * q + jj; \
      acc[q][II][jj] += RA[cb] * w0_ + RA[cb + 1] * w1_ + RA[cb + 2] * w2_ \
                      + RB[cb] * w3_ + RB[cb + 1] * w4_ + RB[cb + 2] * w5_ \
                      + RC[cb] * w6_ + RC[cb + 1] * w7_ + RC[cb + 2] * w8_; \
    } \
  } \
} while (0)

  float b0 = bias[oc];
#pragma unroll 1
  for (int p = 0; p < 5; ++p) {
    float acc[5][2][2];
#pragma unroll
    for (int q = 0; q < 5; ++q)
#pragma unroll
      for (int ii = 0; ii < 2; ++ii)
#pragma unroll
        for (int jj = 0; jj < 2; ++jj) acc[q][ii][jj] = b0;
    float R0[12], R1[12], R2[12], R3[12], R4[12], R5[12];
    LOADR(R0, 0, 0); LOADR(R1, 0, 1); LOADR(R2, 0, 2);
    LOADR(R3, 0, 3); LOADR(R4, 1, 0);
    FMAU(0, R0, R1, R2, 0);
    LOADR(R5, 1, 1); LOADR(R0, 1, 2);
    FMAU(1, R1, R2, R3, 0);
    LOADR(R1, 1, 3); LOADR(R2, 2, 0);
    FMAU(0, R4, R5, R0, 1);
    LOADR(R3, 2, 1); LOADR(R4, 2, 2);
    FMAU(1, R5, R0, R1, 1);
    LOADR(R5, 2, 3); LOADR(R0, 3, 0);
    FMAU(0, R2, R3, R4, 2);
    LOADR(R1, 3, 1); LOADR(R2, 3, 2);
    FMAU(1, R3, R4, R5, 2);
    LOADR(R3, 3, 3);
    FMAU(0, R0, R1, R2, 3);
    FMAU(1, R1, R2, R3, 3);
#pragma unroll
    for (int q = 0; q < 5; ++q) {
      float m = fmaxf(fmaxf(acc[q][0][0], acc[q][0][1]),
                      fmaxf(acc[q][1][0], acc[q][1][1]));
      m = fmaxf(m, 0.f);
      p1[(size_t)(oc * 25 + p * 5 + q) * BT + i0 + item] = m;
    }
  }
#undef LOADR
#undef FMAU
}

// ============ K1 variant B (FALLBACK): r8 exact, measured 164us ===========
__global__ __attribute__((amdgpu_flat_work_group_size(1024, 1024)))
__attribute__((amdgpu_waves_per_eu(4, 4)))
void k1_conv1_big(const float* __restrict__ obs, const float* __restrict__ w,
                  const float* __restrict__ bias, float* __restrict__ p1) {
  __shared__ float xs[64 * 401];
  int tid = threadIdx.x;
  int i0 = blockIdx.x * 64;
  for (int idx = tid; idx < 25600; idx += 1024) {
    int item = idx / 400, feat = idx - item * 400;
    xs[item * 401 + feat] = obs[(size_t)(i0 + item) * 400 + feat];
  }
  __syncthreads();
  int lane = tid & 63;
  int wv = __builtin_amdgcn_readfirstlane(tid >> 6);
  const float* xrow = xs + lane * 401;

#define LOADR(R, C, RR) do { \
  int r_ = 2 * p - 1 + (RR); \
  R[0] = 0.f; R[11] = 0.f; \
  if (r_ >= 0 && r_ <= 9) { \
    _Pragma("unroll") \
    for (int j = 0; j < 10; ++j) R[j + 1] = xrow[(C) * 100 + r_ * 10 + j]; \
  } else { \
    _Pragma("unroll") \
    for (int j = 0; j < 10; ++j) R[j + 1] = 0.f; \
  } \
} while (0)

#define FMAU(II, RA, RB, RC, C) do { \
  const float* wa_ = w + wv * 36 + (C) * 9; \
  _Pragma("unroll") \
  for (int q = 0; q < 5; ++q) { \
    _Pragma("unroll") \
    for (int jj = 0; jj < 2; ++jj) { \
      int cb = 2 * q + jj; \
      acc[q][II][jj] += RA[cb] * wa_[0] + RA[cb + 1] * wa_[1] + RA[cb + 2] * wa_[2] \
                      + RB[cb] * wa_[3] + RB[cb + 1] * wa_[4] + RB[cb + 2] * wa_[5] \
                      + RC[cb] * wa_[6] + RC[cb + 1] * wa_[7] + RC[cb + 2] * wa_[8]; \
    } \
  } \
} while (0)

  float b0 = bias[wv];
#pragma unroll 1
  for (int p = 0; p < 5; ++p) {
    float acc[5][2][2];
#pragma unroll
    for (int q = 0; q < 5; ++q)
#pragma unroll
      for (int ii = 0; ii < 2; ++ii)
#pragma unroll
        for (int jj = 0; jj < 2; ++jj) acc[q][ii][jj] = b0;
    float R0[12], R1[12], R2[12], R3[12], R4[12], R5[12];
    LOADR(R0, 0, 0); LOADR(R1, 0, 1); LOADR(R2, 0, 2);
    LOADR(R3, 0, 3); LOADR(R4, 1, 0);
    FMAU(0, R0, R1, R2, 0);
    LOADR(R5, 1, 1); LOADR(R0, 1, 2);
    FMAU(1, R1, R2, R3, 0);
    LOADR(R1, 1, 3); LOADR(R2, 2, 0);
    FMAU(0, R4, R5, R0, 1);
    LOADR(R3, 2, 1); LOADR(R4, 2, 2);
    FMAU(1, R5, R0, R1, 1);
    LOADR(R5, 2, 3); LOADR(R0, 3, 0);
    FMAU(0, R2, R3, R4, 2);
    LOADR(R1, 3, 1); LOADR(R2, 3, 2);
    FMAU(1, R3, R4, R5, 2);
    LOADR(R3, 3, 3);
    FMAU(0, R0, R1, R2, 3);
    FMAU(1, R1, R2, R3, 3);
#pragma unroll
    for (int q = 0; q < 5; ++q) {
      float m = fmaxf(fmaxf(acc[q][0][0], acc[q][0][1]),
                      fmaxf(acc[q][1][0], acc[q][1][1]));
      m = fmaxf(m, 0.f);
      p1[(size_t)(wv * 25 + p * 5 + q) * BT + i0 + lane] = m;
    }
  }
#undef LOADR
#undef FMAU
}

// ================= K2: conv2 (SAME 3x3, 16->32) + relu + 2x2 maxpool ======
// r13: oc-split 8->4 per block (acc 128->64 VGPR, demand ~150 -> 3
// waves/SIMD) + double-buffered in[] (next-c's 25 loads issued under the
// current c's 576 FMAs). 8 partner blocks (same item group g, oc-groups
// 0..7) share phys%8 -> same XCD L2 and are dispatch-adjacent, so the 8x
// logical p1 re-read stays L2-resident. Per-output FMA order unchanged.
__global__ __launch_bounds__(256, 2)
void k2_conv2(const float* __restrict__ p1, const float* __restrict__ w,
              const float* __restrict__ bias, float* __restrict__ x) {
  int phys = blockIdx.x;            // 1600 blocks
  int x8 = phys & 7;
  int inner = phys >> 3;            // 0..199
  int ocg = inner & 7;              // 4-oc group 0..7
  int g = ((inner >> 3) << 3) | x8; // 0..199, bijective
  int item = g * 256 + threadIdx.x;
  float acc[4][16];
#pragma unroll
  for (int o = 0; o < 4; ++o) {
    float bv = bias[ocg * 4 + o];
#pragma unroll
    for (int pos = 0; pos < 16; ++pos) acc[o][pos] = bv;
  }
  float inA[6][6], inB[6][6];
#define K2LOAD(BUF, C) do { \
  _Pragma("unroll") \
  for (int t = 0; t < 6; ++t) { BUF[0][t] = 0.f; BUF[t][0] = 0.f; } \
  _Pragma("unroll") \
  for (int i = 0; i < 5; ++i) \
    _Pragma("unroll") \
    for (int j = 0; j < 5; ++j) \
      BUF[i + 1][j + 1] = p1[(size_t)((C) * 25 + i * 5 + j) * BT + item]; \
} while (0)
#define K2FMA(BUF, C) do { \
  _Pragma("unroll") \
  for (int o = 0; o < 4; ++o) \
    _Pragma("unroll") \
    for (int i = 0; i < 4; ++i) \
      _Pragma("unroll") \
      for (int j = 0; j < 4; ++j) { \
        float a = acc[o][i * 4 + j]; \
        _Pragma("unroll") \
        for (int dr = 0; dr < 3; ++dr) \
          _Pragma("unroll") \
          for (int dj = 0; dj < 3; ++dj) \
            a += BUF[i + dr][j + dj] * w[((ocg * 4 + o) * 16 + (C)) * 9 + dr * 3 + dj]; \
        acc[o][i * 4 + j] = a; \
      } \
} while (0)
  K2LOAD(inA, 0);
#pragma unroll 1
  for (int c = 0; c < 16; c += 2) {
    K2LOAD(inB, c + 1);           // prefetch odd channel under even FMAs
    K2FMA(inA, c);
    if (c + 2 < 16) K2LOAD(inA, c + 2);  // prefetch next even channel
    K2FMA(inB, c + 1);
  }
#undef K2LOAD
#undef K2FMA
#pragma unroll
  for (int o = 0; o < 4; ++o)
#pragma unroll
    for (int p = 0; p < 2; ++p)
#pragma unroll
      for (int q = 0; q < 2; ++q) {
        float m = fmaxf(fmaxf(acc[o][(2 * p) * 4 + 2 * q], acc[o][(2 * p) * 4 + 2 * q + 1]),
                        fmaxf(acc[o][(2 * p + 1) * 4 + 2 * q], acc[o][(2 * p + 1) * 4 + 2 * q + 1]));
        m = fmaxf(m, 0.f);
        x[(size_t)((ocg * 4 + o) * 4 + p * 2 + q) * BT + item] = m;
      }
}

// ================= K3: fc1(+bn,relu) -> fc2(+bn,relu) -> eWih projection ===
// (r12, kept: 512 thr / 8 waves, 2 blocks/CU -> 4 waves/SIMD)
__global__ __launch_bounds__(512, 1)
void k3_fc(const float* __restrict__ x,
           const float* __restrict__ f1w, const float* __restrict__ f1b,
           const float* __restrict__ bn1g, const float* __restrict__ bn1b,
           const float* __restrict__ f2w, const float* __restrict__ f2b,
           const float* __restrict__ bn2g, const float* __restrict__ bn2b,
           const float* __restrict__ eWih, const float* __restrict__ ebih,
           const float* __restrict__ ebhh, float* __restrict__ gx) {
  __shared__ float xs[128 * 64];
  __shared__ float ys[64 * 129];   // fc1 out [gate][item]; then [item][129]
  const float BNRS = 0.9999950000374997f;  // 1/sqrt(1+1e-5)
  int tid = threadIdx.x;
  int lane = tid & 63;
  int wv = __builtin_amdgcn_readfirstlane(tid >> 6);  // 0..7
  int i0 = blockIdx.x * 64;
  for (int idx = tid; idx < 8192; idx += 512) {
    int k = idx >> 6, l = idx & 63;
    xs[k * 64 + l] = x[(size_t)k * BT + i0 + l];
  }
  __syncthreads();
  // fc1: 128 outputs, 16 per wave
#pragma unroll 1
  for (int jj = 0; jj < 4; ++jj) {
    int j0 = wv * 16 + jj * 4;
    float a[4] = {0.f, 0.f, 0.f, 0.f};
#pragma unroll 8
    for (int k = 0; k < 128; ++k) {
      float xv = xs[k * 64 + lane];
#pragma unroll
      for (int u = 0; u < 4; ++u) a[u] += xv * f1w[(j0 + u) * 128 + k];
    }
#pragma unroll
    for (int u = 0; u < 4; ++u) {
      int j = j0 + u;
      float v = a[u] + f1b[j];
      v = bn1g[j] * v * BNRS + bn1b[j];
      ys[j * 64 + lane] = fmaxf(v, 0.f);
    }
  }
  __syncthreads();
  // fc2: 64 outputs, 8 per wave
#pragma unroll 1
  for (int jj = 0; jj < 2; ++jj) {
    int j0 = wv * 8 + jj * 4;
    float a[4] = {0.f, 0.f, 0.f, 0.f};
#pragma unroll 8
    for (int k = 0; k < 128; ++k) {
      float yv = ys[k * 64 + lane];
#pragma unroll
      for (int u = 0; u < 4; ++u) a[u] += yv * f2w[(j0 + u) * 128 + k];
    }
#pragma unroll
    for (int u = 0; u < 4; ++u) {
      int j = j0 + u;
      float v = a[u] + f2b[j];
      v = bn2g[j] * v * BNRS + bn2b[j];
      xs[j * 64 + lane] = fmaxf(v, 0.f);
    }
  }
  __syncthreads();
  // eWih projection: 128 outputs, 16 per wave -> staged [item][gate]
#pragma unroll 1
  for (int jj = 0; jj < 4; ++jj) {
    int j0 = wv * 16 + jj * 4;
    float a[4] = {0.f, 0.f, 0.f, 0.f};
#pragma unroll 8
    for (int k = 0; k < 64; ++k) {
      float zv = xs[k * 64 + lane];
#pragma unroll
      for (int u = 0; u < 4; ++u) a[u] += zv * eWih[(j0 + u) * 64 + k];
    }
#pragma unroll
    for (int u = 0; u < 4; ++u) {
      int j = j0 + u;
      ys[lane * 129 + j] = a[u] + ebih[j] + ebhh[j];
    }
  }
  __syncthreads();
  // coalesced write-out: per item, 128 contiguous gates
  for (int idx = tid; idx < 8192; idx += 512) {
    int item = idx >> 7, j = idx & 127;
    gx[(size_t)(i0 + item) * 128 + j] = ys[item * 129 + j];
  }
}

// ====== K456: fused encoder LSTM + decoder/physics/QR + Kalman filter =====
// r13: gx prefetch deepened to distance 2 (doubles latency slack per
// encoder step at 2 waves/CU). Otherwise r11 structure. Bit-exact.
__global__ __launch_bounds__(128, 2)
void k456(const float* __restrict__ obs, const float* __restrict__ gx,
          const float* __restrict__ eWhh,
          const float* __restrict__ dWih, const float* __restrict__ dWhh,
          const float* __restrict__ dbih, const float* __restrict__ dbhh,
          const float* __restrict__ ow, const float* __restrict__ ob,
          const float* __restrict__ qWih, const float* __restrict__ qWhh,
          const float* __restrict__ qbih, const float* __restrict__ qbhh,
          const float* __restrict__ qfw, const float* __restrict__ qfb,
          const float* __restrict__ rWih, const float* __restrict__ rWhh,
          const float* __restrict__ rbih, const float* __restrict__ rbhh,
          const float* __restrict__ rfw, const float* __restrict__ rfb,
          float* __restrict__ out) {
  __shared__ float arena[8064];
  __shared__ float tL2[2 * 120];
  int tid = threadIdx.x;
  int lane = tid & 63, w = tid >> 6;   // w in 0..1
  int b = blockIdx.x * 2 + w;
  float* tL = tL2 + w * 120;
  int xl = (lane & 31) + 32;
  int l12 = lane < 12 ? lane : 0;
  int l24 = lane < 24 ? lane : 0;

  // ---------- Phase A: encoder LSTM (T=100), weights in registers --------
  float wA[32], wB[32];
#pragma unroll
  for (int k = 0; k < 32; ++k) {
    wA[k] = eWhh[lane * 32 + k];
    wB[k] = eWhh[(lane + 64) * 32 + k];
  }
  float cc = 0.f, hh = 0.f;
  size_t base0 = (size_t)b * 100;
  float gaP1 = gx[(base0 + 0) * 128 + lane];
  float gbP1 = gx[(base0 + 0) * 128 + 64 + lane];
  float gaP2 = gx[(base0 + 1) * 128 + lane];
  float gbP2 = gx[(base0 + 1) * 128 + 64 + lane];
#pragma unroll 1
  for (int t = 0; t < 100; ++t) {
    float ga = gaP1, gb2 = gbP1;
    gaP1 = gaP2; gbP1 = gbP2;
    if (t < 98) {
      gaP2 = gx[(base0 + t + 2) * 128 + lane];
      gbP2 = gx[(base0 + t + 2) * 128 + 64 + lane];
    }
#pragma unroll
    for (int k = 0; k < 32; ++k) {
      float hk = rl(hh, k);
      ga += hk * wA[k];
      gb2 += hk * wB[k];
    }
    float gaX = __shfl(ga, xl);
    float gbX = __shfl(gb2, xl);
    if (lane < 32) {
      float ig = sigf(ga), fg = sigf(gaX);
      float gg = tanhf2(gb2), og = sigf(gbX);
      cc = fg * cc + ig * gg;
      hh = og * tanhf2(cc);
    }
  }

  // ---------- Phase B: decoder LSTM (5 steps) + physics ----------
  __syncthreads();
  for (int idx = tid; idx < 4096; idx += 128) {
    int k = idx >> 7, g = idx & 127;
    arena[idx] = dWih[g * 32 + k] + dWhh[g * 32 + k];  // din==dh every step
  }
  for (int idx = tid; idx < 384; idx += 128) {
    int k = idx / 12, j = idx - k * 12;
    arena[4096 + idx] = ow[j * 32 + k];
  }
  for (int idx = tid; idx < 128; idx += 128)
    arena[4480 + idx] = dbih[idx] + dbhh[idx];
  __syncthreads();
  {
    const float* dwT = arena;
    const float* owT = arena + 4096;
    const float* dbs = arena + 4480;
    float aReg[5];
#pragma unroll 1
    for (int s = 0; s < 5; ++s) {
      float ga = dbs[lane], gb2 = dbs[lane + 64];
#pragma unroll
      for (int k = 0; k < 32; ++k) {
        float hk = rl(hh, k);
        ga += hk * dwT[k * 128 + lane];
        gb2 += hk * dwT[k * 128 + lane + 64];
      }
      float gaX = __shfl(ga, xl);
      float gbX = __shfl(gb2, xl);
      if (lane < 32) {
        float ig = sigf(ga), fg = sigf(gaX);
        float gg = tanhf2(gb2), og = sigf(gbX);
        cc = fg * cc + ig * gg;
        hh = og * tanhf2(cc);
      }
      float pa = ob[l12];
#pragma unroll
      for (int k = 0; k < 32; ++k) pa += rl(hh, k) * owT[k * 12 + l12];
      aReg[s] = pa;
    }
    if (lane < 12) {
      int n = lane >> 1, d = lane & 1;
      float v0 = 0.f, p0 = 0.f;
      if (n == 0) {
        p0 = obs[(size_t)b * 40000 + 39600 + d];
        v0 = obs[(size_t)b * 40000 + 39600 + 2 + d];
      }
      float vc = v0, pc = p0;
#pragma unroll
      for (int s = 0; s < 5; ++s) {
        float a = aReg[s];
        vc += 0.1f * a;
        pc += vc * 0.1f + a * 0.005f;
        tL[s * 24 + n * 4 + d] = pc;
        tL[s * 24 + n * 4 + 2 + d] = vc;
      }
    }
  }

  // ---------- Phase C: Q then R LSTMs over traj ----------
  float qdiag = 0.f, rdiag = 0.f;
#pragma unroll 1
  for (int qr = 0; qr < 2; ++qr) {
    __syncthreads();
    const float* Wih = qr ? rWih : qWih;
    const float* Whh = qr ? rWhh : qWhh;
    const float* bih = qr ? rbih : qbih;
    const float* bhh = qr ? rbhh : qbhh;
    const float* fw  = qr ? rfw  : qfw;
    const float* fb  = qr ? rfb  : qfb;
    for (int idx = tid; idx < 3072; idx += 128) {
      int k = idx >> 7, g = idx & 127;
      arena[idx] = Wih[g * 24 + k];
    }
    for (int idx = tid; idx < 4096; idx += 128) {
      int k = idx >> 7, g = idx & 127;
      arena[3072 + idx] = Whh[g * 32 + k];
    }
    for (int idx = tid; idx < 768; idx += 128) {
      int k = idx / 24, j = idx - k * 24;
      arena[7168 + idx] = fw[j * 32 + k];
    }
    for (int idx = tid; idx < 128; idx += 128)
      arena[7936 + idx] = bih[idx] + bhh[idx];
    __syncthreads();
    const float* ihT = arena;
    const float* hhT = arena + 3072;
    const float* fwT = arena + 7168;
    const float* bs  = arena + 7936;
    hh = 0.f;
    cc = 0.f;
#pragma unroll 1
    for (int s = 0; s < 5; ++s) {
      float ga = bs[lane], gb2 = bs[lane + 64];
#pragma unroll
      for (int k = 0; k < 24; ++k) {
        float z = tL[s * 24 + k];
        ga += z * ihT[k * 128 + lane];
        gb2 += z * ihT[k * 128 + lane + 64];
      }
#pragma unroll
      for (int k = 0; k < 32; ++k) {
        float hk = rl(hh, k);
        ga += hk * hhT[k * 128 + lane];
        gb2 += hk * hhT[k * 128 + lane + 64];
      }
      float gaX = __shfl(ga, xl);
      float gbX = __shfl(gb2, xl);
      if (lane < 32) {
        float ig = sigf(ga), fg = sigf(gaX);
        float gg = tanhf2(gb2), og = sigf(gbX);
        cc = fg * cc + ig * gg;
        hh = og * tanhf2(cc);
      }
    }
    float qv = fb[l24];
#pragma unroll
    for (int k = 0; k < 32; ++k) qv += rl(hh, k) * fwT[k * 24 + l24];
    if (qr == 0) qdiag = fabsf(qv); else rdiag = fabsf(qv);
  }

  // ---------- Phase D: Kalman filter (register-resident) ------
  {
    float sv = 0.f, qv = 0.f, rv = 0.f;
    if (lane < 24) {
      sv = (lane < 4) ? obs[(size_t)b * 40000 + 39600 + lane] : 0.f;
      qv = qdiag;
      rv = rdiag;
    }
    float p[24];
#pragma unroll
    for (int i = 0; i < 24; ++i) p[i] = (i == lane) ? 1.f : 0.f;
    const int srcPF = ((lane & 3) < 2) ? (lane + 2) : lane;
    const int srcA = (lane < 24) ? lane : (lane - 24);
#pragma unroll 1
    for (int s = 0; s < 5; ++s) {
      float sshift = __shfl(sv, srcPF);
      float smv = sv + (((lane & 3) < 2) ? 0.1f * sshift : 0.f);
#pragma unroll
      for (int i = 0; i < 24; ++i)
        if ((i & 3) < 2) p[i] += 0.1f * p[i + 2];
#pragma unroll
      for (int i = 0; i < 24; ++i) {
        float t = __shfl(p[i], srcPF);
        if ((lane & 3) < 2) p[i] += 0.1f * t;
      }
#pragma unroll
      for (int i = 0; i < 24; ++i) p[i] += (i == lane) ? qv : 0.f;
      float a[24];
#pragma unroll
      for (int i = 0; i < 24; ++i) {
        float t = __shfl(p[i], srcA);
        a[i] = (lane < 24) ? (p[i] + ((i == lane) ? rv : 0.f)) : t;
      }
#pragma unroll
      for (int k = 0; k < 24; ++k) {
        float piv = rl(a[k], k);
        float inv = 1.f / piv;
        float t = a[k] * inv;
#pragma unroll
        for (int i = 0; i < 24; ++i) {
          if (i != k) {
            float fi = rl(a[i], k);
            a[i] = fmaf(-fi, t, a[i]);
          }
        }
        a[k] = t;
      }
      float zv = tL[s * 24 + l24];
      float innv = zv - smv;
      float acc = 0.f;
#pragma unroll
      for (int m = 0; m < 24; ++m) acc += a[m] * rl(innv, m);
      float kupd = __shfl(acc, 24 + l24);
      sv = smv + kupd;
      if (lane < 24) out[(size_t)b * 120 + s * 24 + lane] = sv;
      float pn[24];
#pragma unroll
      for (int i = 0; i < 24; ++i) {
        float acc2 = 0.f;
#pragma unroll
        for (int k = 0; k < 24; ++k) acc2 += rl(a[k], 24 + i) * p[k];
        pn[i] = p[i] - acc2;
      }
#pragma unroll
      for (int i = 0; i < 24; ++i) p[i] = pn[i];
    }
  }
}

// =========================================================================
extern "C" void kernel_launch(void* const* d_in, const int* in_sizes, int n_in,
                              void* d_out, int out_size, void* d_ws, size_t ws_size,
                              hipStream_t stream) {
  (void)in_sizes; (void)n_in; (void)out_size; (void)ws_size;
  const float* obs  = (const float*)d_in[0];
  const float* c1w  = (const float*)d_in[1];
  const float* c1b  = (const float*)d_in[2];
  const float* c2w  = (const float*)d_in[3];
  const float* c2b  = (const float*)d_in[4];
  const float* f1w  = (const float*)d_in[5];
  const float* f1b  = (const float*)d_in[6];
  const float* bn1g = (const float*)d_in[7];
  const float* bn1b = (const float*)d_in[8];
  const float* f2w  = (const float*)d_in[9];
  const float* f2b  = (const float*)d_in[10];
  const float* bn2g = (const float*)d_in[11];
  const float* bn2b = (const float*)d_in[12];
  const float* eWih = (const float*)d_in[13];
  const float* eWhh = (const float*)d_in[14];
  const float* ebih = (const float*)d_in[15];
  const float* ebhh = (const float*)d_in[16];
  const float* dWih = (const float*)d_in[17];
  const float* dWhh = (const float*)d_in[18];
  const float* dbih = (const float*)d_in[19];
  const float* dbhh = (const float*)d_in[20];
  const float* ow   = (const float*)d_in[21];
  const float* ob   = (const float*)d_in[22];
  const float* qWih = (const float*)d_in[23];
  const float* qWhh = (const float*)d_in[24];
  const float* qbih = (const float*)d_in[25];
  const float* qbhh = (const float*)d_in[26];
  const float* qfw  = (const float*)d_in[27];
  const float* qfb  = (const float*)d_in[28];
  const float* rWih = (const float*)d_in[29];
  const float* rWhh = (const float*)d_in[30];
  const float* rbih = (const float*)d_in[31];
  const float* rbhh = (const float*)d_in[32];
  const float* rfw  = (const float*)d_in[33];
  const float* rfb  = (const float*)d_in[34];

  float* ws = (float*)d_ws;
  float* p1   = ws + P1_OFF;
  float* x    = ws + X_OFF;
  float* gx   = ws + GX_OFF;       // reuses p1 region (dead after k2)
  float* out  = (float*)d_out;

  // Runtime guard against the allocator's 64-VGPR squeeze (r9 lesson).
  static int k1_use_exp = -1;
  if (k1_use_exp < 0) {
    hipFuncAttributes attr;
    hipError_t e = hipFuncGetAttributes(&attr, (const void*)k1_conv1_exp);
    k1_use_exp = (e == hipSuccess && attr.numRegs >= 100) ? 1 : 0;
  }
  if (k1_use_exp)
    k1_conv1_exp<<<1600, 512, 0, stream>>>(obs, c1w, c1b, p1);
  else
    k1_conv1_big<<<800, 1024, 0, stream>>>(obs, c1w, c1b, p1);

  k2_conv2<<<1600, 256, 0, stream>>>(p1, c2w, c2b, x);
  k3_fc<<<800, 512, 0, stream>>>(x, f1w, f1b, bn1g, bn1b, f2w, f2b, bn2g, bn2b,
                                 eWih, ebih, ebhh, gx);
  k456<<<256, 128, 0, stream>>>(obs, gx, eWhh,
                                dWih, dWhh, dbih, dbhh, ow, ob,
                                qWih, qWhh, qbih, qbhh, qfw, qfb,
                                rWih, rWhh, rbih, rbhh, rfw, rfb,
                                out);
}

// Round 14
// 574.943 us; speedup vs baseline: 1.0554x; 1.0554x over previous
//
#include <hip/hip_runtime.h>

#define BT 51200      // B*T
#define NB 512        // batch

// ---------- workspace float offsets ----------
#define P1_OFF   ((size_t)0)
#define X_OFF    ((size_t)20480000)
#define GX_OFF   ((size_t)0)

__device__ __forceinline__ float sigf(float x) {
  return __fdividef(1.f, 1.f + __expf(-x));
}
__device__ __forceinline__ float tanhf2(float x) {
  float ax = fabsf(x);
  float e = __expf(-2.f * ax);
  float r = __fdividef(1.f - e, 1.f + e);
  return x < 0.f ? -r : r;
}
// broadcast of lane `l` (uniform/literal index): v_readlane, VALU-only.
__device__ __forceinline__ float rl(float v, int l) {
  return __uint_as_float(__builtin_amdgcn_readlane(__float_as_uint(v), l));
}

// ============ K1 variant A (EXPERIMENTAL): 512thr / 32 items ==============
// (r10/r11: VGPR 124, FETCH 40MB, WRITE 80MB, VALUBusy 77%, 146us — clean,
// near VALU limit. Frozen.)
__global__ __launch_bounds__(512, 1)
void k1_conv1_exp(const float* __restrict__ obs, const float* __restrict__ w,
                  const float* __restrict__ bias, float* __restrict__ p1) {
  __shared__ float xs[32 * 411];   // 411 odd -> item*411 mod 32 permutation
  __shared__ float wsh[16 * 36];
  int tid = threadIdx.x;
  int phys = blockIdx.x;           // 1600 blocks
  int x8 = phys & 7;
  int rest = phys >> 3;            // 0..199
  int half = rest & 1;
  int pair = (rest >> 1) * 8 + x8; // 0..799
  int i0 = pair * 64 + half * 32;
  for (int idx = tid; idx < 12800; idx += 512) {
    int item = idx / 400, feat = idx - item * 400;
    xs[item * 411 + feat] = obs[(size_t)(i0 + item) * 400 + feat];
  }
  for (int idx = tid; idx < 576; idx += 512) wsh[idx] = w[idx];
  __syncthreads();
  int lane = tid & 63;
  int item = lane & 31;
  int oc = (tid >> 6) * 2 + (lane >> 5);
  const float* xrow = xs + item * 411;

#define LOADR(R, C, RR) do { \
  int r_ = 2 * p - 1 + (RR); \
  R[0] = 0.f; R[11] = 0.f; \
  if (r_ >= 0 && r_ <= 9) { \
    _Pragma("unroll") \
    for (int j = 0; j < 10; ++j) R[j + 1] = xrow[(C) * 100 + r_ * 10 + j]; \
  } else { \
    _Pragma("unroll") \
    for (int j = 0; j < 10; ++j) R[j + 1] = 0.f; \
  } \
} while (0)

#define FMAU(II, RA, RB, RC, C) do { \
  const float* wp_ = wsh + oc * 36 + (C) * 9; \
  float w0_ = wp_[0], w1_ = wp_[1], w2_ = wp_[2]; \
  float w3_ = wp_[3], w4_ = wp_[4], w5_ = wp_[5]; \
  float w6_ = wp_[6], w7_ = wp_[7], w8_ = wp_[8]; \
  _Pragma("unroll") \
  for (int q = 0; q < 5; ++q) { \
    _Pragma("unroll") \
    for (int jj = 0; jj < 2; ++jj) { \
      int cb = 2 * q + jj; \
      acc[q][II][jj] += RA[cb] * w0_ + RA[cb + 1] * w1_ + RA[cb + 2] * w2_ \
                      + RB[cb] * w3_ + RB[cb + 1] * w4_ + RB[cb + 2] * w5_ \
                      + RC[cb] * w6_ + RC[cb + 1] * w7_ + RC[cb + 2] * w8_; \
    } \
  } \
} while (0)

  float b0 = bias[oc];
#pragma unroll 1
  for (int p = 0; p < 5; ++p) {
    float acc[5][2][2];
#pragma unroll
    for (int q = 0; q < 5; ++q)
#pragma unroll
      for (int ii = 0; ii < 2; ++ii)
#pragma unroll
        for (int jj = 0; jj < 2; ++jj) acc[q][ii][jj] = b0;
    float R0[12], R1[12], R2[12], R3[12], R4[12], R5[12];
    LOADR(R0, 0, 0); LOADR(R1, 0, 1); LOADR(R2, 0, 2);
    LOADR(R3, 0, 3); LOADR(R4, 1, 0);
    FMAU(0, R0, R1, R2, 0);
    LOADR(R5, 1, 1); LOADR(R0, 1, 2);
    FMAU(1, R1, R2, R3, 0);
    LOADR(R1, 1, 3); LOADR(R2, 2, 0);
    FMAU(0, R4, R5, R0, 1);
    LOADR(R3, 2, 1); LOADR(R4, 2, 2);
    FMAU(1, R5, R0, R1, 1);
    LOADR(R5, 2, 3); LOADR(R0, 3, 0);
    FMAU(0, R2, R3, R4, 2);
    LOADR(R1, 3, 1); LOADR(R2, 3, 2);
    FMAU(1, R3, R4, R5, 2);
    LOADR(R3, 3, 3);
    FMAU(0, R0, R1, R2, 3);
    FMAU(1, R1, R2, R3, 3);
#pragma unroll
    for (int q = 0; q < 5; ++q) {
      float m = fmaxf(fmaxf(acc[q][0][0], acc[q][0][1]),
                      fmaxf(acc[q][1][0], acc[q][1][1]));
      m = fmaxf(m, 0.f);
      p1[(size_t)(oc * 25 + p * 5 + q) * BT + i0 + item] = m;
    }
  }
#undef LOADR
#undef FMAU
}

// ============ K1 variant B (FALLBACK): r8 exact, measured 164us ===========
__global__ __attribute__((amdgpu_flat_work_group_size(1024, 1024)))
__attribute__((amdgpu_waves_per_eu(4, 4)))
void k1_conv1_big(const float* __restrict__ obs, const float* __restrict__ w,
                  const float* __restrict__ bias, float* __restrict__ p1) {
  __shared__ float xs[64 * 401];
  int tid = threadIdx.x;
  int i0 = blockIdx.x * 64;
  for (int idx = tid; idx < 25600; idx += 1024) {
    int item = idx / 400, feat = idx - item * 400;
    xs[item * 401 + feat] = obs[(size_t)(i0 + item) * 400 + feat];
  }
  __syncthreads();
  int lane = tid & 63;
  int wv = __builtin_amdgcn_readfirstlane(tid >> 6);
  const float* xrow = xs + lane * 401;

#define LOADR(R, C, RR) do { \
  int r_ = 2 * p - 1 + (RR); \
  R[0] = 0.f; R[11] = 0.f; \
  if (r_ >= 0 && r_ <= 9) { \
    _Pragma("unroll") \
    for (int j = 0; j < 10; ++j) R[j + 1] = xrow[(C) * 100 + r_ * 10 + j]; \
  } else { \
    _Pragma("unroll") \
    for (int j = 0; j < 10; ++j) R[j + 1] = 0.f; \
  } \
} while (0)

#define FMAU(II, RA, RB, RC, C) do { \
  const float* wa_ = w + wv * 36 + (C) * 9; \
  _Pragma("unroll") \
  for (int q = 0; q < 5; ++q) { \
    _Pragma("unroll") \
    for (int jj = 0; jj < 2; ++jj) { \
      int cb = 2 * q + jj; \
      acc[q][II][jj] += RA[cb] * wa_[0] + RA[cb + 1] * wa_[1] + RA[cb + 2] * wa_[2] \
                      + RB[cb] * wa_[3] + RB[cb + 1] * wa_[4] + RB[cb + 2] * wa_[5] \
                      + RC[cb] * wa_[6] + RC[cb + 1] * wa_[7] + RC[cb + 2] * wa_[8]; \
    } \
  } \
} while (0)

  float b0 = bias[wv];
#pragma unroll 1
  for (int p = 0; p < 5; ++p) {
    float acc[5][2][2];
#pragma unroll
    for (int q = 0; q < 5; ++q)
#pragma unroll
      for (int ii = 0; ii < 2; ++ii)
#pragma unroll
        for (int jj = 0; jj < 2; ++jj) acc[q][ii][jj] = b0;
    float R0[12], R1[12], R2[12], R3[12], R4[12], R5[12];
    LOADR(R0, 0, 0); LOADR(R1, 0, 1); LOADR(R2, 0, 2);
    LOADR(R3, 0, 3); LOADR(R4, 1, 0);
    FMAU(0, R0, R1, R2, 0);
    LOADR(R5, 1, 1); LOADR(R0, 1, 2);
    FMAU(1, R1, R2, R3, 0);
    LOADR(R1, 1, 3); LOADR(R2, 2, 0);
    FMAU(0, R4, R5, R0, 1);
    LOADR(R3, 2, 1); LOADR(R4, 2, 2);
    FMAU(1, R5, R0, R1, 1);
    LOADR(R5, 2, 3); LOADR(R0, 3, 0);
    FMAU(0, R2, R3, R4, 2);
    LOADR(R1, 3, 1); LOADR(R2, 3, 2);
    FMAU(1, R3, R4, R5, 2);
    LOADR(R3, 3, 3);
    FMAU(0, R0, R1, R2, 3);
    FMAU(1, R1, R2, R3, 3);
#pragma unroll
    for (int q = 0; q < 5; ++q) {
      float m = fmaxf(fmaxf(acc[q][0][0], acc[q][0][1]),
                      fmaxf(acc[q][1][0], acc[q][1][1]));
      m = fmaxf(m, 0.f);
      p1[(size_t)(wv * 25 + p * 5 + q) * BT + i0 + lane] = m;
    }
  }
#undef LOADR
#undef FMAU
}

// ================= K2: conv2 (SAME 3x3, 16->32) + relu + 2x2 maxpool ======
// r14: LDS-tiled (the k1 recipe). 16 items/block, ALL 32 oc in-block
// (2 per thread) -> p1 read exactly once, no partner re-reads. The 400
// global loads/thread (each needing a 64b address add: stride 204800B >
// any imm field -> ~800 VALU overhead, the r13 limiter at VALUBusy 63%)
// become ds_reads with COMPILE-TIME imm offsets (base=item*4, off=row*64
// <= 25.6K): zero address VALU. Tile reads: 16 banks x 4-way broadcast
// (free). Weights transposed [c*9+t][33]: 8 consecutive banks x 8-way
// broadcast (free). LDS 44.6KB -> 3 blocks/CU = 3 waves/SIMD. 64B
// store/load segments: pair-swizzle puts both halves of each 128B line
// on the same XCD. FMA chain per output unchanged -> bit-exact.
__global__ __launch_bounds__(256, 2)
void k2_conv2(const float* __restrict__ p1, const float* __restrict__ w,
              const float* __restrict__ bias, float* __restrict__ x) {
  __shared__ float tile[400 * 16];   // [ch*25+pos][item] 25.6KB
  __shared__ float wT[144 * 33];     // [c*9+t][oc] pad 33, 19.0KB
  int tid = threadIdx.x;
  int phys = blockIdx.x;             // 3200 blocks
  int x8 = phys & 7;
  int rest = phys >> 3;              // 0..399
  int half = rest & 1;
  int pair = (rest >> 1) * 8 + x8;   // 0..1599
  int i0 = pair * 32 + half * 16;
  for (int idx = tid; idx < 6400; idx += 256) {
    int row = idx >> 4, item = idx & 15;
    tile[row * 16 + item] = p1[(size_t)row * BT + i0 + item];
  }
  for (int idx = tid; idx < 4608; idx += 256) {
    int oc = idx & 31, ct = idx >> 5;   // ct = c*9+t
    wT[ct * 33 + oc] = w[(size_t)(oc * 16 + (ct / 9)) * 9 + (ct % 9)];
  }
  __syncthreads();
  int item = tid & 15;
  int slot = tid >> 4;       // 0..15 -> oc {2*slot, 2*slot+1}
  const float* trow = tile + item;
  float acc[2][16];
#pragma unroll
  for (int u = 0; u < 2; ++u) {
    float bv = bias[slot * 2 + u];
#pragma unroll
    for (int pos = 0; pos < 16; ++pos) acc[u][pos] = bv;
  }
#pragma unroll 1
  for (int c = 0; c < 16; ++c) {
    float in[6][6];
#pragma unroll
    for (int t = 0; t < 6; ++t) { in[0][t] = 0.f; in[t][0] = 0.f; }
#pragma unroll
    for (int i = 0; i < 5; ++i)
#pragma unroll
      for (int j = 0; j < 5; ++j)
        in[i + 1][j + 1] = trow[(c * 25 + i * 5 + j) * 16];
#pragma unroll
    for (int u = 0; u < 2; ++u) {
      int oc = slot * 2 + u;
#pragma unroll
      for (int i = 0; i < 4; ++i)
#pragma unroll
        for (int j = 0; j < 4; ++j) {
          float a = acc[u][i * 4 + j];
#pragma unroll
          for (int dr = 0; dr < 3; ++dr)
#pragma unroll
            for (int dj = 0; dj < 3; ++dj)
              a += in[i + dr][j + dj] * wT[(c * 9 + dr * 3 + dj) * 33 + oc];
          acc[u][i * 4 + j] = a;
        }
    }
  }
#pragma unroll
  for (int u = 0; u < 2; ++u) {
    int oc = slot * 2 + u;
#pragma unroll
    for (int p = 0; p < 2; ++p)
#pragma unroll
      for (int q = 0; q < 2; ++q) {
        float m = fmaxf(fmaxf(acc[u][(2 * p) * 4 + 2 * q], acc[u][(2 * p) * 4 + 2 * q + 1]),
                        fmaxf(acc[u][(2 * p + 1) * 4 + 2 * q], acc[u][(2 * p + 1) * 4 + 2 * q + 1]));
        m = fmaxf(m, 0.f);
        x[(size_t)(oc * 4 + p * 2 + q) * BT + i0 + item] = m;
      }
  }
}

// ================= K3: fc1(+bn,relu) -> fc2(+bn,relu) -> eWih projection ===
// (r12, kept: 512 thr / 8 waves, 2 blocks/CU -> 4 waves/SIMD)
__global__ __launch_bounds__(512, 1)
void k3_fc(const float* __restrict__ x,
           const float* __restrict__ f1w, const float* __restrict__ f1b,
           const float* __restrict__ bn1g, const float* __restrict__ bn1b,
           const float* __restrict__ f2w, const float* __restrict__ f2b,
           const float* __restrict__ bn2g, const float* __restrict__ bn2b,
           const float* __restrict__ eWih, const float* __restrict__ ebih,
           const float* __restrict__ ebhh, float* __restrict__ gx) {
  __shared__ float xs[128 * 64];
  __shared__ float ys[64 * 129];   // fc1 out [gate][item]; then [item][129]
  const float BNRS = 0.9999950000374997f;  // 1/sqrt(1+1e-5)
  int tid = threadIdx.x;
  int lane = tid & 63;
  int wv = __builtin_amdgcn_readfirstlane(tid >> 6);  // 0..7
  int i0 = blockIdx.x * 64;
  for (int idx = tid; idx < 8192; idx += 512) {
    int k = idx >> 6, l = idx & 63;
    xs[k * 64 + l] = x[(size_t)k * BT + i0 + l];
  }
  __syncthreads();
  // fc1: 128 outputs, 16 per wave
#pragma unroll 1
  for (int jj = 0; jj < 4; ++jj) {
    int j0 = wv * 16 + jj * 4;
    float a[4] = {0.f, 0.f, 0.f, 0.f};
#pragma unroll 8
    for (int k = 0; k < 128; ++k) {
      float xv = xs[k * 64 + lane];
#pragma unroll
      for (int u = 0; u < 4; ++u) a[u] += xv * f1w[(j0 + u) * 128 + k];
    }
#pragma unroll
    for (int u = 0; u < 4; ++u) {
      int j = j0 + u;
      float v = a[u] + f1b[j];
      v = bn1g[j] * v * BNRS + bn1b[j];
      ys[j * 64 + lane] = fmaxf(v, 0.f);
    }
  }
  __syncthreads();
  // fc2: 64 outputs, 8 per wave
#pragma unroll 1
  for (int jj = 0; jj < 2; ++jj) {
    int j0 = wv * 8 + jj * 4;
    float a[4] = {0.f, 0.f, 0.f, 0.f};
#pragma unroll 8
    for (int k = 0; k < 128; ++k) {
      float yv = ys[k * 64 + lane];
#pragma unroll
      for (int u = 0; u < 4; ++u) a[u] += yv * f2w[(j0 + u) * 128 + k];
    }
#pragma unroll
    for (int u = 0; u < 4; ++u) {
      int j = j0 + u;
      float v = a[u] + f2b[j];
      v = bn2g[j] * v * BNRS + bn2b[j];
      xs[j * 64 + lane] = fmaxf(v, 0.f);
    }
  }
  __syncthreads();
  // eWih projection: 128 outputs, 16 per wave -> staged [item][gate]
#pragma unroll 1
  for (int jj = 0; jj < 4; ++jj) {
    int j0 = wv * 16 + jj * 4;
    float a[4] = {0.f, 0.f, 0.f, 0.f};
#pragma unroll 8
    for (int k = 0; k < 64; ++k) {
      float zv = xs[k * 64 + lane];
#pragma unroll
      for (int u = 0; u < 4; ++u) a[u] += zv * eWih[(j0 + u) * 64 + k];
    }
#pragma unroll
    for (int u = 0; u < 4; ++u) {
      int j = j0 + u;
      ys[lane * 129 + j] = a[u] + ebih[j] + ebhh[j];
    }
  }
  __syncthreads();
  // coalesced write-out: per item, 128 contiguous gates
  for (int idx = tid; idx < 8192; idx += 512) {
    int item = idx >> 7, j = idx & 127;
    gx[(size_t)(i0 + item) * 128 + j] = ys[item * 129 + j];
  }
}

// ====== K456: fused encoder LSTM + decoder/physics/QR + Kalman filter =====
// (r13, kept: reg-resident encoder weights, readlane broadcasts, coalesced
// gx, prefetch depth 2)
__global__ __launch_bounds__(128, 2)
void k456(const float* __restrict__ obs, const float* __restrict__ gx,
          const float* __restrict__ eWhh,
          const float* __restrict__ dWih, const float* __restrict__ dWhh,
          const float* __restrict__ dbih, const float* __restrict__ dbhh,
          const float* __restrict__ ow, const float* __restrict__ ob,
          const float* __restrict__ qWih, const float* __restrict__ qWhh,
          const float* __restrict__ qbih, const float* __restrict__ qbhh,
          const float* __restrict__ qfw, const float* __restrict__ qfb,
          const float* __restrict__ rWih, const float* __restrict__ rWhh,
          const float* __restrict__ rbih, const float* __restrict__ rbhh,
          const float* __restrict__ rfw, const float* __restrict__ rfb,
          float* __restrict__ out) {
  __shared__ float arena[8064];
  __shared__ float tL2[2 * 120];
  int tid = threadIdx.x;
  int lane = tid & 63, w = tid >> 6;   // w in 0..1
  int b = blockIdx.x * 2 + w;
  float* tL = tL2 + w * 120;
  int xl = (lane & 31) + 32;
  int l12 = lane < 12 ? lane : 0;
  int l24 = lane < 24 ? lane : 0;

  // ---------- Phase A: encoder LSTM (T=100), weights in registers --------
  float wA[32], wB[32];
#pragma unroll
  for (int k = 0; k < 32; ++k) {
    wA[k] = eWhh[lane * 32 + k];
    wB[k] = eWhh[(lane + 64) * 32 + k];
  }
  float cc = 0.f, hh = 0.f;
  size_t base0 = (size_t)b * 100;
  float gaP1 = gx[(base0 + 0) * 128 + lane];
  float gbP1 = gx[(base0 + 0) * 128 + 64 + lane];
  float gaP2 = gx[(base0 + 1) * 128 + lane];
  float gbP2 = gx[(base0 + 1) * 128 + 64 + lane];
#pragma unroll 1
  for (int t = 0; t < 100; ++t) {
    float ga = gaP1, gb2 = gbP1;
    gaP1 = gaP2; gbP1 = gbP2;
    if (t < 98) {
      gaP2 = gx[(base0 + t + 2) * 128 + lane];
      gbP2 = gx[(base0 + t + 2) * 128 + 64 + lane];
    }
#pragma unroll
    for (int k = 0; k < 32; ++k) {
      float hk = rl(hh, k);
      ga += hk * wA[k];
      gb2 += hk * wB[k];
    }
    float gaX = __shfl(ga, xl);
    float gbX = __shfl(gb2, xl);
    if (lane < 32) {
      float ig = sigf(ga), fg = sigf(gaX);
      float gg = tanhf2(gb2), og = sigf(gbX);
      cc = fg * cc + ig * gg;
      hh = og * tanhf2(cc);
    }
  }

  // ---------- Phase B: decoder LSTM (5 steps) + physics ----------
  __syncthreads();
  for (int idx = tid; idx < 4096; idx += 128) {
    int k = idx >> 7, g = idx & 127;
    arena[idx] = dWih[g * 32 + k] + dWhh[g * 32 + k];  // din==dh every step
  }
  for (int idx = tid; idx < 384; idx += 128) {
    int k = idx / 12, j = idx - k * 12;
    arena[4096 + idx] = ow[j * 32 + k];
  }
  for (int idx = tid; idx < 128; idx += 128)
    arena[4480 + idx] = dbih[idx] + dbhh[idx];
  __syncthreads();
  {
    const float* dwT = arena;
    const float* owT = arena + 4096;
    const float* dbs = arena + 4480;
    float aReg[5];
#pragma unroll 1
    for (int s = 0; s < 5; ++s) {
      float ga = dbs[lane], gb2 = dbs[lane + 64];
#pragma unroll
      for (int k = 0; k < 32; ++k) {
        float hk = rl(hh, k);
        ga += hk * dwT[k * 128 + lane];
        gb2 += hk * dwT[k * 128 + lane + 64];
      }
      float gaX = __shfl(ga, xl);
      float gbX = __shfl(gb2, xl);
      if (lane < 32) {
        float ig = sigf(ga), fg = sigf(gaX);
        float gg = tanhf2(gb2), og = sigf(gbX);
        cc = fg * cc + ig * gg;
        hh = og * tanhf2(cc);
      }
      float pa = ob[l12];
#pragma unroll
      for (int k = 0; k < 32; ++k) pa += rl(hh, k) * owT[k * 12 + l12];
      aReg[s] = pa;
    }
    if (lane < 12) {
      int n = lane >> 1, d = lane & 1;
      float v0 = 0.f, p0 = 0.f;
      if (n == 0) {
        p0 = obs[(size_t)b * 40000 + 39600 + d];
        v0 = obs[(size_t)b * 40000 + 39600 + 2 + d];
      }
      float vc = v0, pc = p0;
#pragma unroll
      for (int s = 0; s < 5; ++s) {
        float a = aReg[s];
        vc += 0.1f * a;
        pc += vc * 0.1f + a * 0.005f;
        tL[s * 24 + n * 4 + d] = pc;
        tL[s * 24 + n * 4 + 2 + d] = vc;
      }
    }
  }

  // ---------- Phase C: Q then R LSTMs over traj ----------
  float qdiag = 0.f, rdiag = 0.f;
#pragma unroll 1
  for (int qr = 0; qr < 2; ++qr) {
    __syncthreads();
    const float* Wih = qr ? rWih : qWih;
    const float* Whh = qr ? rWhh : qWhh;
    const float* bih = qr ? rbih : qbih;
    const float* bhh = qr ? rbhh : qbhh;
    const float* fw  = qr ? rfw  : qfw;
    const float* fb  = qr ? rfb  : qfb;
    for (int idx = tid; idx < 3072; idx += 128) {
      int k = idx >> 7, g = idx & 127;
      arena[idx] = Wih[g * 24 + k];
    }
    for (int idx = tid; idx < 4096; idx += 128) {
      int k = idx >> 7, g = idx & 127;
      arena[3072 + idx] = Whh[g * 32 + k];
    }
    for (int idx = tid; idx < 768; idx += 128) {
      int k = idx / 24, j = idx - k * 24;
      arena[7168 + idx] = fw[j * 32 + k];
    }
    for (int idx = tid; idx < 128; idx += 128)
      arena[7936 + idx] = bih[idx] + bhh[idx];
    __syncthreads();
    const float* ihT = arena;
    const float* hhT = arena + 3072;
    const float* fwT = arena + 7168;
    const float* bs  = arena + 7936;
    hh = 0.f;
    cc = 0.f;
#pragma unroll 1
    for (int s = 0; s < 5; ++s) {
      float ga = bs[lane], gb2 = bs[lane + 64];
#pragma unroll
      for (int k = 0; k < 24; ++k) {
        float z = tL[s * 24 + k];
        ga += z * ihT[k * 128 + lane];
        gb2 += z * ihT[k * 128 + lane + 64];
      }
#pragma unroll
      for (int k = 0; k < 32; ++k) {
        float hk = rl(hh, k);
        ga += hk * hhT[k * 128 + lane];
        gb2 += hk * hhT[k * 128 + lane + 64];
      }
      float gaX = __shfl(ga, xl);
      float gbX = __shfl(gb2, xl);
      if (lane < 32) {
        float ig = sigf(ga), fg = sigf(gaX);
        float gg = tanhf2(gb2), og = sigf(gbX);
        cc = fg * cc + ig * gg;
        hh = og * tanhf2(cc);
      }
    }
    float qv = fb[l24];
#pragma unroll
    for (int k = 0; k < 32; ++k) qv += rl(hh, k) * fwT[k * 24 + l24];
    if (qr == 0) qdiag = fabsf(qv); else rdiag = fabsf(qv);
  }

  // ---------- Phase D: Kalman filter (register-resident) ------
  {
    float sv = 0.f, qv = 0.f, rv = 0.f;
    if (lane < 24) {
      sv = (lane < 4) ? obs[(size_t)b * 40000 + 39600 + lane] : 0.f;
      qv = qdiag;
      rv = rdiag;
    }
    float p[24];
#pragma unroll
    for (int i = 0; i < 24; ++i) p[i] = (i == lane) ? 1.f : 0.f;
    const int srcPF = ((lane & 3) < 2) ? (lane + 2) : lane;
    const int srcA = (lane < 24) ? lane : (lane - 24);
#pragma unroll 1
    for (int s = 0; s < 5; ++s) {
      float sshift = __shfl(sv, srcPF);
      float smv = sv + (((lane & 3) < 2) ? 0.1f * sshift : 0.f);
#pragma unroll
      for (int i = 0; i < 24; ++i)
        if ((i & 3) < 2) p[i] += 0.1f * p[i + 2];
#pragma unroll
      for (int i = 0; i < 24; ++i) {
        float t = __shfl(p[i], srcPF);
        if ((lane & 3) < 2) p[i] += 0.1f * t;
      }
#pragma unroll
      for (int i = 0; i < 24; ++i) p[i] += (i == lane) ? qv : 0.f;
      float a[24];
#pragma unroll
      for (int i = 0; i < 24; ++i) {
        float t = __shfl(p[i], srcA);
        a[i] = (lane < 24) ? (p[i] + ((i == lane) ? rv : 0.f)) : t;
      }
#pragma unroll
      for (int k = 0; k < 24; ++k) {
        float piv = rl(a[k], k);
        float inv = 1.f / piv;
        float t = a[k] * inv;
#pragma unroll
        for (int i = 0; i < 24; ++i) {
          if (i != k) {
            float fi = rl(a[i], k);
            a[i] = fmaf(-fi, t, a[i]);
          }
        }
        a[k] = t;
      }
      float zv = tL[s * 24 + l24];
      float innv = zv - smv;
      float acc = 0.f;
#pragma unroll
      for (int m = 0; m < 24; ++m) acc += a[m] * rl(innv, m);
      float kupd = __shfl(acc, 24 + l24);
      sv = smv + kupd;
      if (lane < 24) out[(size_t)b * 120 + s * 24 + lane] = sv;
      float pn[24];
#pragma unroll
      for (int i = 0; i < 24; ++i) {
        float acc2 = 0.f;
#pragma unroll
        for (int k = 0; k < 24; ++k) acc2 += rl(a[k], 24 + i) * p[k];
        pn[i] = p[i] - acc2;
      }
#pragma unroll
      for (int i = 0; i < 24; ++i) p[i] = pn[i];
    }
  }
}

// =========================================================================
extern "C" void kernel_launch(void* const* d_in, const int* in_sizes, int n_in,
                              void* d_out, int out_size, void* d_ws, size_t ws_size,
                              hipStream_t stream) {
  (void)in_sizes; (void)n_in; (void)out_size; (void)ws_size;
  const float* obs  = (const float*)d_in[0];
  const float* c1w  = (const float*)d_in[1];
  const float* c1b  = (const float*)d_in[2];
  const float* c2w  = (const float*)d_in[3];
  const float* c2b  = (const float*)d_in[4];
  const float* f1w  = (const float*)d_in[5];
  const float* f1b  = (const float*)d_in[6];
  const float* bn1g = (const float*)d_in[7];
  const float* bn1b = (const float*)d_in[8];
  const float* f2w  = (const float*)d_in[9];
  const float* f2b  = (const float*)d_in[10];
  const float* bn2g = (const float*)d_in[11];
  const float* bn2b = (const float*)d_in[12];
  const float* eWih = (const float*)d_in[13];
  const float* eWhh = (const float*)d_in[14];
  const float* ebih = (const float*)d_in[15];
  const float* ebhh = (const float*)d_in[16];
  const float* dWih = (const float*)d_in[17];
  const float* dWhh = (const float*)d_in[18];
  const float* dbih = (const float*)d_in[19];
  const float* dbhh = (const float*)d_in[20];
  const float* ow   = (const float*)d_in[21];
  const float* ob   = (const float*)d_in[22];
  const float* qWih = (const float*)d_in[23];
  const float* qWhh = (const float*)d_in[24];
  const float* qbih = (const float*)d_in[25];
  const float* qbhh = (const float*)d_in[26];
  const float* qfw  = (const float*)d_in[27];
  const float* qfb  = (const float*)d_in[28];
  const float* rWih = (const float*)d_in[29];
  const float* rWhh = (const float*)d_in[30];
  const float* rbih = (const float*)d_in[31];
  const float* rbhh = (const float*)d_in[32];
  const float* rfw  = (const float*)d_in[33];
  const float* rfb  = (const float*)d_in[34];

  float* ws = (float*)d_ws;
  float* p1   = ws + P1_OFF;
  float* x    = ws + X_OFF;
  float* gx   = ws + GX_OFF;       // reuses p1 region (dead after k2)
  float* out  = (float*)d_out;

  // Runtime guard against the allocator's 64-VGPR squeeze (r9 lesson).
  static int k1_use_exp = -1;
  if (k1_use_exp < 0) {
    hipFuncAttributes attr;
    hipError_t e = hipFuncGetAttributes(&attr, (const void*)k1_conv1_exp);
    k1_use_exp = (e == hipSuccess && attr.numRegs >= 100) ? 1 : 0;
  }
  if (k1_use_exp)
    k1_conv1_exp<<<1600, 512, 0, stream>>>(obs, c1w, c1b, p1);
  else
    k1_conv1_big<<<800, 1024, 0, stream>>>(obs, c1w, c1b, p1);

  k2_conv2<<<3200, 256, 0, stream>>>(p1, c2w, c2b, x);
  k3_fc<<<800, 512, 0, stream>>>(x, f1w, f1b, bn1g, bn1b, f2w, f2b, bn2g, bn2b,
                                 eWih, ebih, ebhh, gx);
  k456<<<256, 128, 0, stream>>>(obs, gx, eWhh,
                                dWih, dWhh, dbih, dbhh, ow, ob,
                                qWih, qWhh, qbih, qbhh, qfw, qfb,
                                rWih, rWhh, rbih, rbhh, rfw, rfb,
                                out);
}